// Round 1
// baseline (296.116 us; speedup 1.0000x reference)
//
#include <hip/hip_runtime.h>

namespace {

constexpr int kB = 2;
constexpr int kN = 16384;
constexpr int kC = 256;
constexpr int kM = 16;
constexpr int kW = kN / kM;        // 1024 windows total
constexpr int kWOut = 64;          // only windows < 64 reach the output
constexpr int kQRows = kWOut * kM; // 1024 q rows needed per batch

__device__ __forceinline__ float phi_act(float x) {
  // elu(elu(x)+1)+1 ; since elu(x)+1 > 0, outer elu is identity:
  //   x > 0 : x + 2 ; x <= 0 : exp(x) + 1
  return x > 0.f ? x + 2.f : __expf(x) + 1.f;
}

// Y[b, n, :] = phi(X[b, n, :] @ Wm + bias) for n < ROWS_PER_B, both batches.
// Tiled SGEMM: 64x64 tile, 256 threads, 4x4 micro-tile, BK=16.
template <int ROWS_PER_B>
__global__ __launch_bounds__(256) void proj_kernel(
    const float* __restrict__ X, const float* __restrict__ Wm,
    const float* __restrict__ bias, float* __restrict__ Y) {
  __shared__ float As[16][68];  // [k][row]
  __shared__ float Bs[16][68];  // [k][col]
  const int tid = threadIdx.x;
  const int ty = tid >> 4, tx = tid & 15;
  const int r0 = blockIdx.x * 64;  // global row tile (never straddles batch)
  const int b = r0 / ROWS_PER_B;
  const int n0 = r0 % ROWS_PER_B;
  const int j0 = blockIdx.y * 64;  // output col tile
  const float* Xt = X + ((size_t)b * kN + n0) * kC;

  const int la_row = tid >> 2;        // 0..63
  const int la_k4 = (tid & 3) << 2;   // 0,4,8,12
  const int lb_k = tid >> 4;          // 0..15
  const int lb_j4 = (tid & 15) << 2;  // 0..60

  float acc[4][4] = {};
  for (int k0 = 0; k0 < kC; k0 += 16) {
    const float4 av = *reinterpret_cast<const float4*>(
        Xt + (size_t)la_row * kC + k0 + la_k4);
    const float4 bv = *reinterpret_cast<const float4*>(
        Wm + (size_t)(k0 + lb_k) * kC + j0 + lb_j4);
    __syncthreads();
    As[la_k4 + 0][la_row] = av.x;
    As[la_k4 + 1][la_row] = av.y;
    As[la_k4 + 2][la_row] = av.z;
    As[la_k4 + 3][la_row] = av.w;
    *reinterpret_cast<float4*>(&Bs[lb_k][lb_j4]) = bv;
    __syncthreads();
#pragma unroll
    for (int kk = 0; kk < 16; ++kk) {
      float a[4], bb[4];
#pragma unroll
      for (int i = 0; i < 4; ++i) a[i] = As[kk][ty * 4 + i];
#pragma unroll
      for (int j = 0; j < 4; ++j) bb[j] = Bs[kk][tx * 4 + j];
#pragma unroll
      for (int i = 0; i < 4; ++i)
#pragma unroll
        for (int j = 0; j < 4; ++j) acc[i][j] = fmaf(a[i], bb[j], acc[i][j]);
    }
  }
  const float4 b4 = *reinterpret_cast<const float4*>(bias + j0 + tx * 4);
#pragma unroll
  for (int i = 0; i < 4; ++i) {
    float4 o;
    o.x = phi_act(acc[i][0] + b4.x);
    o.y = phi_act(acc[i][1] + b4.y);
    o.z = phi_act(acc[i][2] + b4.z);
    o.w = phi_act(acc[i][3] + b4.w);
    *reinterpret_cast<float4*>(Y + (size_t)(r0 + ty * 4 + i) * kC + j0 +
                               tx * 4) = o;
  }
}

// KV[b, m, c, d] = sum_w PhiK[b, w*16+m, c] * V[b, w*16+m, d]
// One (b,m) pair per blockIdx.z; 64x64 output tile; reduce over w in 16-chunks.
__global__ __launch_bounds__(256) void kv_kernel(const float* __restrict__ PhiK,
                                                 const float* __restrict__ V,
                                                 float* __restrict__ KV) {
  __shared__ float As[16][68];  // [w][c]
  __shared__ float Bs[16][68];  // [w][d]
  const int tid = threadIdx.x;
  const int ty = tid >> 4, tx = tid & 15;
  const int bm = blockIdx.z;
  const int b = bm >> 4, m = bm & 15;
  const int c0 = blockIdx.x * 64, d0 = blockIdx.y * 64;
  const int lw = tid >> 4;            // 0..15 (w within chunk)
  const int lc4 = (tid & 15) << 2;    // 0..60
  const size_t rowbase = (size_t)b * kN * kC + (size_t)m * kC;

  float acc[4][4] = {};
  for (int w0 = 0; w0 < kW; w0 += 16) {
    const size_t roff = rowbase + (size_t)(w0 + lw) * (kM * kC);
    const float4 av = *reinterpret_cast<const float4*>(PhiK + roff + c0 + lc4);
    const float4 bv = *reinterpret_cast<const float4*>(V + roff + d0 + lc4);
    __syncthreads();
    *reinterpret_cast<float4*>(&As[lw][lc4]) = av;
    *reinterpret_cast<float4*>(&Bs[lw][lc4]) = bv;
    __syncthreads();
#pragma unroll
    for (int kk = 0; kk < 16; ++kk) {
      float a[4], bb[4];
#pragma unroll
      for (int i = 0; i < 4; ++i) a[i] = As[kk][ty * 4 + i];
#pragma unroll
      for (int j = 0; j < 4; ++j) bb[j] = Bs[kk][tx * 4 + j];
#pragma unroll
      for (int i = 0; i < 4; ++i)
#pragma unroll
        for (int j = 0; j < 4; ++j) acc[i][j] = fmaf(a[i], bb[j], acc[i][j]);
    }
  }
  float* o = KV + (size_t)bm * kC * kC;
#pragma unroll
  for (int i = 0; i < 4; ++i) {
    float4 v4;
    v4.x = acc[i][0];
    v4.y = acc[i][1];
    v4.z = acc[i][2];
    v4.w = acc[i][3];
    *reinterpret_cast<float4*>(o + (size_t)(c0 + ty * 4 + i) * kC + d0 +
                               tx * 4) = v4;
  }
}

// Out[b, qr*16+m, d] = sum_c PhiQ[b, qr, c] * KV[b, m, c, d] + p[b, qr>>4, qr&15, m]
__global__ __launch_bounds__(256) void out_kernel(
    const float* __restrict__ PhiQ, const float* __restrict__ KV,
    const float* __restrict__ EQK, const float* __restrict__ Wp,
    const float* __restrict__ bpp, float* __restrict__ Out) {
  __shared__ float As[16][68];  // [k=c][qrow]
  __shared__ float Bs[16][68];  // [k=c][d]
  __shared__ float Ps[64];
  const int tid = threadIdx.x;
  const int ty = tid >> 4, tx = tid & 15;
  const int bm = blockIdx.z;
  const int b = bm >> 4, m = bm & 15;
  const int q0 = blockIdx.x * 64, d0 = blockIdx.y * 64;

  if (tid < 64) {
    const int qr = q0 + tid;
    const int w = qr >> 4, nn = qr & 15;
    const float* e = EQK + ((((size_t)b * kW + w) * kM + nn) * kM + m) * 3;
    Ps[tid] = e[0] * Wp[0] + e[1] * Wp[1] + e[2] * Wp[2] + bpp[0];
  }

  const int la_row = tid >> 2;
  const int la_k4 = (tid & 3) << 2;
  const int lb_k = tid >> 4;
  const int lb_j4 = (tid & 15) << 2;
  const float* Aq = PhiQ + (size_t)b * kQRows * kC;
  const float* Bk = KV + (size_t)bm * kC * kC;

  float acc[4][4] = {};
  for (int k0 = 0; k0 < kC; k0 += 16) {
    const float4 av = *reinterpret_cast<const float4*>(
        Aq + (size_t)(q0 + la_row) * kC + k0 + la_k4);
    const float4 bv = *reinterpret_cast<const float4*>(
        Bk + (size_t)(k0 + lb_k) * kC + d0 + lb_j4);
    __syncthreads();
    As[la_k4 + 0][la_row] = av.x;
    As[la_k4 + 1][la_row] = av.y;
    As[la_k4 + 2][la_row] = av.z;
    As[la_k4 + 3][la_row] = av.w;
    *reinterpret_cast<float4*>(&Bs[lb_k][lb_j4]) = bv;
    __syncthreads();
#pragma unroll
    for (int kk = 0; kk < 16; ++kk) {
      float a[4], bb[4];
#pragma unroll
      for (int i = 0; i < 4; ++i) a[i] = As[kk][ty * 4 + i];
#pragma unroll
      for (int j = 0; j < 4; ++j) bb[j] = Bs[kk][tx * 4 + j];
#pragma unroll
      for (int i = 0; i < 4; ++i)
#pragma unroll
        for (int j = 0; j < 4; ++j) acc[i][j] = fmaf(a[i], bb[j], acc[i][j]);
    }
  }
#pragma unroll
  for (int i = 0; i < 4; ++i) {
    const int qr = q0 + ty * 4 + i;
    const float p = Ps[ty * 4 + i];
    float4 o;
    o.x = acc[i][0] + p;
    o.y = acc[i][1] + p;
    o.z = acc[i][2] + p;
    o.w = acc[i][3] + p;
    *reinterpret_cast<float4*>(Out + ((size_t)b * kN + (size_t)qr * kM + m) * kC +
                               d0 + tx * 4) = o;
  }
}

}  // namespace

extern "C" void kernel_launch(void* const* d_in, const int* in_sizes, int n_in,
                              void* d_out, int out_size, void* d_ws,
                              size_t ws_size, hipStream_t stream) {
  const float* input = (const float*)d_in[0];  // [B][N][C]
  const float* eqk = (const float*)d_in[1];    // [B][W][M][M][3]
  const float* Wq = (const float*)d_in[2];     // [C][C]
  const float* bq = (const float*)d_in[3];     // [C]
  const float* Wk = (const float*)d_in[4];     // [C][C]
  const float* bk = (const float*)d_in[5];     // [C]
  const float* Wp = (const float*)d_in[6];     // [3]
  const float* bp = (const float*)d_in[7];     // [1]
  float* out = (float*)d_out;                  // [B][N][C]

  // Workspace layout (fp32): phi_k | phi_q | KV  => 32MB + 2MB + 8MB
  float* phi_k = (float*)d_ws;                    // [B][N][C]
  float* phi_q = phi_k + (size_t)kB * kN * kC;    // [B][kQRows][C]
  float* kv = phi_q + (size_t)kB * kQRows * kC;   // [B][M][C][C]

  dim3 blk(256);
  proj_kernel<kN><<<dim3(kB * kN / 64, kC / 64), blk, 0, stream>>>(input, Wk,
                                                                   bk, phi_k);
  proj_kernel<kQRows><<<dim3(kB * kQRows / 64, kC / 64), blk, 0, stream>>>(
      input, Wq, bq, phi_q);
  kv_kernel<<<dim3(kC / 64, kC / 64, kB * kM), blk, 0, stream>>>(phi_k, input,
                                                                 kv);
  out_kernel<<<dim3(kQRows / 64, kC / 64, kB * kM), blk, 0, stream>>>(
      phi_q, kv, eqk, Wp, bp, out);
}

// Round 2
// 163.751 us; speedup vs baseline: 1.8083x; 1.8083x over previous
//
#include <hip/hip_runtime.h>

typedef __attribute__((ext_vector_type(8))) short s16x8;
typedef __attribute__((ext_vector_type(8))) ushort u16x8;
typedef __attribute__((ext_vector_type(4))) ushort u16x4;
typedef __attribute__((ext_vector_type(4))) float f32x4v;

namespace {

constexpr int kB = 2;
constexpr int kN = 16384;
constexpr int kC = 256;

__device__ __forceinline__ ushort f2bf(float f) {
  union { float f; uint u; } v; v.f = f;
  uint u = v.u + 0x7fffu + ((v.u >> 16) & 1u);
  return (ushort)(u >> 16);
}

__device__ __forceinline__ float phi_act(float x) {
  return x > 0.f ? x + 2.f : __expf(x) + 1.f;
}

// ---- shared MFMA micro-kernel: A/B tiles in LDS as [row][32k] bf16, 16B-chunk
// swizzled with chunk' = chunk ^ ((row>>1)&3). Slot map k=(lane>>4)*8+j applied
// identically to A and B (valid by A/B slot symmetry).
template <int FM, int FN>
__device__ __forceinline__ void wave_mma(const ushort* __restrict__ A,
                                         const ushort* __restrict__ B, int ar0,
                                         int bc0, int lane,
                                         f32x4v acc[FM][FN]) {
  const int lo = lane & 15, hi = lane >> 4;
  s16x8 a[FM], b[FN];
#pragma unroll
  for (int i = 0; i < FM; ++i) {
    int r = ar0 + i * 16 + lo;
    a[i] = *reinterpret_cast<const s16x8*>(A + r * 32 + ((hi ^ ((r >> 1) & 3)) << 3));
  }
#pragma unroll
  for (int j = 0; j < FN; ++j) {
    int c = bc0 + j * 16 + lo;
    b[j] = *reinterpret_cast<const s16x8*>(B + c * 32 + ((hi ^ ((c >> 1) & 3)) << 3));
  }
#pragma unroll
  for (int i = 0; i < FM; ++i)
#pragma unroll
    for (int j = 0; j < FN; ++j)
      acc[i][j] = __builtin_amdgcn_mfma_f32_16x16x32_bf16(a[i], b[j], acc[i][j], 0, 0, 0);
}

// ---- 1. weight transpose+convert: W[k][j] f32 -> WT[j][k] bf16
__global__ __launch_bounds__(256) void wt_kernel(const float* __restrict__ Wq,
                                                 const float* __restrict__ Wk,
                                                 ushort* __restrict__ WqT,
                                                 ushort* __restrict__ WkT) {
  __shared__ float ts[64][65];
  const float* W = blockIdx.z ? Wk : Wq;
  ushort* WT = blockIdx.z ? WkT : WqT;
  const int bi = blockIdx.x, bj = blockIdx.y, t = threadIdx.x;
  for (int rep = 0; rep < 16; ++rep) {
    int e = rep * 256 + t, r = e >> 6, c = e & 63;
    ts[r][c] = W[(size_t)(bi * 64 + r) * kC + bj * 64 + c];
  }
  __syncthreads();
  for (int rep = 0; rep < 16; ++rep) {
    int e = rep * 256 + t, j = e >> 6, k = e & 63;
    WT[(size_t)(bj * 64 + j) * kC + bi * 64 + k] = f2bf(ts[k][j]);
  }
}

// ---- 2. regroup: input f32 [b][n][256] -> bf16 grouped [b][m][wblk(128)][c(256)][8w]
__global__ __launch_bounds__(256) void regroup_kernel(const float* __restrict__ X,
                                                      ushort* __restrict__ G) {
  __shared__ ushort ls[64 * 288];  // [w(64)][m stride 18][c(16)]
  const int cb = blockIdx.x;   // 16 c-blocks of 16
  const int wb = blockIdx.y;   // 16 w-blocks of 64 windows (1024 rows)
  const int b = blockIdx.z;
  const int t = threadIdx.x;
  const float* src = X + ((size_t)b * kN + wb * 1024) * kC + cb * 16;
  const int lr = t >> 2, cg = t & 3;
  for (int rep = 0; rep < 16; ++rep) {
    int row = rep * 64 + lr;  // 0..1023
    float4 v = *reinterpret_cast<const float4*>(src + (size_t)row * kC + cg * 4);
    int w = row >> 4, m = row & 15;
    int base = w * 288 + m * 18 + cg * 4;
    uint p0 = (uint)f2bf(v.x) | ((uint)f2bf(v.y) << 16);
    uint p1 = (uint)f2bf(v.z) | ((uint)f2bf(v.w) << 16);
    *reinterpret_cast<uint*>(ls + base) = p0;
    *reinterpret_cast<uint*>(ls + base + 2) = p1;
  }
  __syncthreads();
  const int m = t >> 4, c_l = t & 15;
  const size_t gbase = ((size_t)b * 16 + m) * 128 + wb * 8;
#pragma unroll
  for (int r = 0; r < 8; ++r) {
    u16x8 v;
#pragma unroll
    for (int wl = 0; wl < 8; ++wl) v[wl] = ls[(r * 8 + wl) * 288 + m * 18 + c_l];
    *reinterpret_cast<u16x8*>(G + (gbase + r) * 2048 + (size_t)(cb * 16 + c_l) * 8) = v;
  }
}

// ---- 3. projection GEMM: phi(X @ W^T-rows + bias). GROUPED: write bf16 grouped
// layout (for phi_k); else plain [row][256] bf16 (for phi_q).
template <bool GROUPED, int RPB>
__global__ __launch_bounds__(256) void proj_kernel(const float* __restrict__ X,
                                                   const ushort* __restrict__ WT,
                                                   const float* __restrict__ bias,
                                                   ushort* __restrict__ Outp) {
  __shared__ __align__(16) ushort smem[16384];
  ushort* Alds = smem;
  ushort* Blds = smem + 4096;
  const int t = threadIdx.x, lane = t & 63, wv = t >> 6;
  const int gr0 = blockIdx.x * 128, jb = blockIdx.y, j0 = jb * 128;
  const int b = gr0 / RPB, n0 = gr0 % RPB;
  const float* Asrc = X + ((size_t)b * kN + n0) * kC;
  const ushort* Bsrc = WT + (size_t)j0 * kC;
  const int ar = t >> 2, aj = t & 3;

  float4 a0[2], a1[2];
  u16x8 rb[2];
  auto loadT = [&](int k0) {
    a0[0] = *reinterpret_cast<const float4*>(Asrc + (size_t)ar * kC + k0 + aj * 8);
    a1[0] = *reinterpret_cast<const float4*>(Asrc + (size_t)ar * kC + k0 + aj * 8 + 4);
    a0[1] = *reinterpret_cast<const float4*>(Asrc + (size_t)(ar + 64) * kC + k0 + aj * 8);
    a1[1] = *reinterpret_cast<const float4*>(Asrc + (size_t)(ar + 64) * kC + k0 + aj * 8 + 4);
    rb[0] = *reinterpret_cast<const u16x8*>(Bsrc + (size_t)ar * kC + k0 + aj * 8);
    rb[1] = *reinterpret_cast<const u16x8*>(Bsrc + (size_t)(ar + 64) * kC + k0 + aj * 8);
  };
  auto writeT = [&]() {
#pragma unroll
    for (int k = 0; k < 2; ++k) {
      int row = ar + 64 * k;
      int ch = aj ^ ((row >> 1) & 3);
      u16x8 v;
      v[0] = f2bf(a0[k].x); v[1] = f2bf(a0[k].y); v[2] = f2bf(a0[k].z); v[3] = f2bf(a0[k].w);
      v[4] = f2bf(a1[k].x); v[5] = f2bf(a1[k].y); v[6] = f2bf(a1[k].z); v[7] = f2bf(a1[k].w);
      *reinterpret_cast<u16x8*>(Alds + row * 32 + ch * 8) = v;
      *reinterpret_cast<u16x8*>(Blds + row * 32 + ch * 8) = rb[k];
    }
  };

  f32x4v acc[4][4] = {};
  const int wr0 = (wv >> 1) * 64, wc0 = (wv & 1) * 64;
  loadT(0);
  for (int ks = 0; ks < 8; ++ks) {
    __syncthreads();
    writeT();
    if (ks < 7) loadT((ks + 1) * 32);
    __syncthreads();
    wave_mma<4, 4>(Alds, Blds, wr0, wc0, lane, acc);
  }

  const int lo = lane & 15, hi = lane >> 4;
  float bv[4];
#pragma unroll
  for (int fj = 0; fj < 4; ++fj) bv[fj] = bias[j0 + wc0 + fj * 16 + lo];

  if (GROUPED) {
    __syncthreads();
#pragma unroll
    for (int fi = 0; fi < 4; ++fi)
#pragma unroll
      for (int fj = 0; fj < 4; ++fj)
#pragma unroll
        for (int r = 0; r < 4; ++r) {
          int row = wr0 + fi * 16 + hi * 4 + r;
          int col = wc0 + fj * 16 + lo;
          smem[row * 128 + col] = f2bf(phi_act(acc[fi][fj][r] + bv[fj]));
        }
    __syncthreads();
    const int wblk = n0 >> 7;
    const int mh = t >> 7, c_l = t & 127;
#pragma unroll
    for (int rep = 0; rep < 8; ++rep) {
      int m = mh * 8 + rep;
      u16x8 v;
#pragma unroll
      for (int wl = 0; wl < 8; ++wl) v[wl] = smem[(wl * 16 + m) * 128 + c_l];
      *reinterpret_cast<u16x8*>(Outp + ((((size_t)b * 16 + m) * 128 + wblk) * 256 + j0 + c_l) * 8) = v;
    }
  } else {
#pragma unroll
    for (int fi = 0; fi < 4; ++fi)
#pragma unroll
      for (int fj = 0; fj < 4; ++fj)
#pragma unroll
        for (int r = 0; r < 4; ++r) {
          int row = gr0 + wr0 + fi * 16 + hi * 4 + r;
          int col = j0 + wc0 + fj * 16 + lo;
          Outp[(size_t)row * kC + col] = f2bf(phi_act(acc[fi][fj][r] + bv[fj]));
        }
  }
}

// ---- 4. KV GEMM per (b,m): KV^T[d][c] = sum_w phik[c][w] * v[d][w], K=1024
__global__ __launch_bounds__(256) void kv_kernel(const ushort* __restrict__ Kg,
                                                 const ushort* __restrict__ Vg,
                                                 ushort* __restrict__ KVT) {
  __shared__ __align__(16) ushort smem[6144];  // A 128x32, B 64x32
  ushort* Alds = smem;
  ushort* Blds = smem + 4096;
  const int t = threadIdx.x, lane = t & 63, wv = t >> 6;
  const int cb = blockIdx.x, db = blockIdx.y, bm = blockIdx.z;
  const ushort* Abase = Kg + (size_t)bm * 262144 + (size_t)(cb * 128) * 8;
  const ushort* Bbase = Vg + (size_t)bm * 262144 + (size_t)(db * 64) * 8;
  const int ac = t & 127, ajh = t >> 7;
  const int bd = t & 63, bj = t >> 6;

  u16x8 ra[2], rbv;
  auto loadT = [&](int s) {
    int w4 = s * 4;
    ra[0] = *reinterpret_cast<const u16x8*>(Abase + ((size_t)(w4 + ajh) * 256 + ac) * 8);
    ra[1] = *reinterpret_cast<const u16x8*>(Abase + ((size_t)(w4 + ajh + 2) * 256 + ac) * 8);
    rbv = *reinterpret_cast<const u16x8*>(Bbase + ((size_t)(w4 + bj) * 256 + bd) * 8);
  };
  auto writeT = [&]() {
    int sw = (ac >> 1) & 3;
    *reinterpret_cast<u16x8*>(Alds + ac * 32 + ((ajh ^ sw) << 3)) = ra[0];
    *reinterpret_cast<u16x8*>(Alds + ac * 32 + (((ajh + 2) ^ sw) << 3)) = ra[1];
    *reinterpret_cast<u16x8*>(Blds + bd * 32 + ((bj ^ ((bd >> 1) & 3)) << 3)) = rbv;
  };

  f32x4v acc[4][2] = {};
  const int wr0 = (wv >> 1) * 64, wc0 = (wv & 1) * 32;
  loadT(0);
  for (int s = 0; s < 32; ++s) {
    __syncthreads();
    writeT();
    if (s < 31) loadT(s + 1);
    __syncthreads();
    wave_mma<4, 2>(Alds, Blds, wr0, wc0, lane, acc);
  }
  const int lo = lane & 15, hi = lane >> 4;
#pragma unroll
  for (int fi = 0; fi < 4; ++fi)
#pragma unroll
    for (int fj = 0; fj < 2; ++fj) {
      int d = db * 64 + wc0 + fj * 16 + lo;
      int c = cb * 128 + wr0 + fi * 16 + hi * 4;
      u16x4 v = {f2bf(acc[fi][fj][0]), f2bf(acc[fi][fj][1]),
                 f2bf(acc[fi][fj][2]), f2bf(acc[fi][fj][3])};
      *reinterpret_cast<u16x4*>(KVT + ((size_t)bm * 256 + d) * 256 + c) = v;
    }
}

// ---- 5. out GEMM per (b,m): Out[qr*16+m][d] = phi_q[qr] . KVT[d] + p
__global__ __launch_bounds__(256) void out_kernel(const ushort* __restrict__ Q,
                                                  const ushort* __restrict__ KVT,
                                                  const float* __restrict__ EQK,
                                                  const float* __restrict__ Wp,
                                                  const float* __restrict__ bp,
                                                  float* __restrict__ Out) {
  __shared__ __align__(16) ushort smem[8192];
  __shared__ float Ps[128];
  ushort* Alds = smem;
  ushort* Blds = smem + 4096;
  const int t = threadIdx.x, lane = t & 63, wv = t >> 6;
  const int qb = blockIdx.x, db = blockIdx.y, bm = blockIdx.z;
  const int b = bm >> 4, m = bm & 15;
  if (t < 128) {
    int qr = qb * 128 + t;
    const float* e = EQK + (((size_t)(b * 1024 + (qr >> 4)) * 16 + (qr & 15)) * 16 + m) * 3;
    Ps[t] = e[0] * Wp[0] + e[1] * Wp[1] + e[2] * Wp[2] + bp[0];
  }
  const ushort* Asrc = Q + ((size_t)b * 1024 + qb * 128) * kC;
  const ushort* Bsrc = KVT + (size_t)bm * 65536 + (size_t)db * 128 * kC;
  const int ar = t >> 2, aj = t & 3;

  u16x8 rga[2], rgb[2];
  auto loadT = [&](int k0) {
    rga[0] = *reinterpret_cast<const u16x8*>(Asrc + (size_t)ar * kC + k0 + aj * 8);
    rga[1] = *reinterpret_cast<const u16x8*>(Asrc + (size_t)(ar + 64) * kC + k0 + aj * 8);
    rgb[0] = *reinterpret_cast<const u16x8*>(Bsrc + (size_t)ar * kC + k0 + aj * 8);
    rgb[1] = *reinterpret_cast<const u16x8*>(Bsrc + (size_t)(ar + 64) * kC + k0 + aj * 8);
  };
  auto writeT = [&]() {
#pragma unroll
    for (int k = 0; k < 2; ++k) {
      int row = ar + 64 * k;
      int ch = aj ^ ((row >> 1) & 3);
      *reinterpret_cast<u16x8*>(Alds + row * 32 + ch * 8) = rga[k];
      *reinterpret_cast<u16x8*>(Blds + row * 32 + ch * 8) = rgb[k];
    }
  };

  f32x4v acc[4][4] = {};
  const int wr0 = (wv >> 1) * 64, wc0 = (wv & 1) * 64;
  loadT(0);
  for (int ks = 0; ks < 8; ++ks) {
    __syncthreads();
    writeT();
    if (ks < 7) loadT((ks + 1) * 32);
    __syncthreads();
    wave_mma<4, 4>(Alds, Blds, wr0, wc0, lane, acc);
  }
  const int lo = lane & 15, hi = lane >> 4;
#pragma unroll
  for (int fi = 0; fi < 4; ++fi)
#pragma unroll
    for (int r = 0; r < 4; ++r) {
      int rowl = wr0 + fi * 16 + hi * 4 + r;
      int qr = qb * 128 + rowl;
      float p = Ps[rowl];
      size_t orow = ((size_t)b * kN + (size_t)qr * 16 + m) * kC;
#pragma unroll
      for (int fj = 0; fj < 4; ++fj) {
        int d = db * 128 + wc0 + fj * 16 + lo;
        Out[orow + d] = acc[fi][fj][r] + p;
      }
    }
}

}  // namespace

extern "C" void kernel_launch(void* const* d_in, const int* in_sizes, int n_in,
                              void* d_out, int out_size, void* d_ws,
                              size_t ws_size, hipStream_t stream) {
  const float* input = (const float*)d_in[0];
  const float* eqk = (const float*)d_in[1];
  const float* Wq = (const float*)d_in[2];
  const float* bq = (const float*)d_in[3];
  const float* Wk = (const float*)d_in[4];
  const float* bk = (const float*)d_in[5];
  const float* Wp = (const float*)d_in[6];
  const float* bp = (const float*)d_in[7];
  float* out = (float*)d_out;

  // ws layout (ushort units): 39.1 MB total
  ushort* ws = (ushort*)d_ws;
  ushort* WqT = ws;                    // 65536
  ushort* WkT = WqT + 65536;           // 65536
  ushort* xg = WkT + 65536;            // 2*16*128*256*8 = 8388608
  ushort* kg = xg + 8388608;           // 8388608
  ushort* qf = kg + 8388608;           // 2048*256 = 524288
  ushort* kvt = qf + 524288;           // 2*16*256*256 = 2097152

  wt_kernel<<<dim3(4, 4, 2), 256, 0, stream>>>(Wq, Wk, WqT, WkT);
  regroup_kernel<<<dim3(16, 16, 2), 256, 0, stream>>>(input, xg);
  proj_kernel<true, 16384><<<dim3(256, 2), 256, 0, stream>>>(input, WkT, bk, kg);
  proj_kernel<false, 1024><<<dim3(16, 2), 256, 0, stream>>>(input, WqT, bq, qf);
  kv_kernel<<<dim3(2, 4, 32), 256, 0, stream>>>(kg, xg, kvt);
  out_kernel<<<dim3(8, 2, 32), 256, 0, stream>>>(qf, kvt, eqk, Wp, bp, out);
}

// Round 7
// 143.726 us; speedup vs baseline: 2.0603x; 1.1393x over previous
//
#include <hip/hip_runtime.h>

typedef __attribute__((ext_vector_type(8))) short s16x8;
typedef __attribute__((ext_vector_type(8))) ushort u16x8;
typedef __attribute__((ext_vector_type(4))) ushort u16x4;
typedef __attribute__((ext_vector_type(4))) float f32x4v;

namespace {

constexpr int kB = 2;
constexpr int kN = 16384;
constexpr int kC = 256;
constexpr int kQR = 1024;  // q rows per batch that reach the output

__device__ __forceinline__ ushort f2bf(float f) {
  union { float f; uint u; } v; v.f = f;
  uint u = v.u + 0x7fffu + ((v.u >> 16) & 1u);
  return (ushort)(u >> 16);
}

__device__ __forceinline__ float phi_act(float x) {
  // elu(elu(x)+1)+1 == x>0 ? x+2 : exp(x)+1
  return x > 0.f ? x + 2.f : __expf(x) + 1.f;
}

// ---- 1. weight transpose+convert: W[k][j] f32 -> WT[j][k] bf16
__global__ __launch_bounds__(256) void wt_kernel(const float* __restrict__ Wq,
                                                 const float* __restrict__ Wk,
                                                 ushort* __restrict__ WqT,
                                                 ushort* __restrict__ WkT) {
  __shared__ float ts[64][65];
  const float* W = blockIdx.z ? Wk : Wq;
  ushort* WT = blockIdx.z ? WkT : WqT;
  const int bi = blockIdx.x, bj = blockIdx.y, t = threadIdx.x;
  for (int rep = 0; rep < 16; ++rep) {
    int e = rep * 256 + t, r = e >> 6, c = e & 63;
    ts[r][c] = W[(size_t)(bi * 64 + r) * kC + bj * 64 + c];
  }
  __syncthreads();
  for (int rep = 0; rep < 16; ++rep) {
    int e = rep * 256 + t, j = e >> 6, k = e & 63;
    WT[(size_t)(bj * 64 + j) * kC + bi * 64 + k] = f2bf(ts[k][j]);
  }
}

// ---- 2. fused projections + v-regroup.
// blocks 0..255: K-mode: rows 128/block over both b; computes phi_k -> kg
//   (grouped [bm][wgrp][c][8w]) and converts input rows -> xg (same layout).
// blocks 256..271: Q-mode: phi_q for rows<1024 per b -> qf flat [row][c].
__global__ __launch_bounds__(512) void proj_fused(
    const float* __restrict__ X, const ushort* __restrict__ WqT,
    const ushort* __restrict__ WkT, const float* __restrict__ bq,
    const float* __restrict__ bk, ushort* __restrict__ xg,
    ushort* __restrict__ kg, ushort* __restrict__ qf) {
  __shared__ __align__(16) ushort smem[24576];  // 48 KB: A dbuf 2x4096, B dbuf 2x8192

  const int t = threadIdx.x, lane = t & 63, wv = t >> 6;
  const int bx = blockIdx.x;
  const bool kmode = bx < 256;
  int b, n0;
  const ushort* WT;
  const float* bias;
  if (kmode) {
    b = bx >> 7; n0 = (bx & 127) * 128; WT = WkT; bias = bk;
  } else {
    int i = bx - 256; b = i >> 3; n0 = (i & 7) * 128; WT = WqT; bias = bq;
  }
  const int wgrp = bx & 127;  // valid in kmode only
  const float* Xbase = X + ((size_t)b * kN + n0) * kC;

  // A-stage mapping: thread owns (m, c) and 8 w's (rows wl*16+m)
  const int m = t >> 5, cl = t & 31;
  // B-stage mapping: thread owns rows bj, bj+128 at chunk bch
  const int bj = t >> 2, bch = t & 3;

  float fa[8];
  u16x8 rb0, rb1;
  auto stageLoad = [&](int ks) {
    const int k0 = ks * 32;
#pragma unroll
    for (int wl = 0; wl < 8; ++wl)
      fa[wl] = Xbase[(size_t)(wl * 16 + m) * kC + k0 + cl];
    rb0 = *reinterpret_cast<const u16x8*>(WT + (size_t)bj * kC + k0 + bch * 8);
    rb1 = *reinterpret_cast<const u16x8*>(WT + (size_t)(bj + 128) * kC + k0 + bch * 8);
  };
  auto stageWrite = [&](int h, int ks) {
    ushort* A = smem + h * 4096;
    ushort* B = smem + 8192 + h * 8192;
    u16x8 vx;
#pragma unroll
    for (int wl = 0; wl < 8; ++wl) {
      int row = wl * 16 + m;
      ushort bf = f2bf(fa[wl]);
      A[row * 32 + (((cl >> 3) ^ ((row >> 1) & 3)) << 3) + (cl & 7)] = bf;
      vx[wl] = bf;
    }
    *reinterpret_cast<u16x8*>(B + bj * 32 + ((bch ^ ((bj >> 1) & 3)) << 3)) = rb0;
    *reinterpret_cast<u16x8*>(B + (bj + 128) * 32 + ((bch ^ (((bj + 128) >> 1) & 3)) << 3)) = rb1;
    if (kmode) {
      *reinterpret_cast<u16x8*>(
          xg + (((size_t)(b * 16 + m) * 128 + wgrp) * 256 + ks * 32 + cl) * 8) = vx;
    }
  };

  f32x4v acc[4][4] = {};
  const int lo = lane & 15, hi = lane >> 4;
  const int wr0 = (wv >> 2) * 64, wc0 = (wv & 3) * 64;
  auto mma = [&](int h) {
    const ushort* A = smem + h * 4096;
    const ushort* B = smem + 8192 + h * 8192;
    s16x8 af[4], bf[4];
#pragma unroll
    for (int i = 0; i < 4; ++i) {
      int r = wr0 + i * 16 + lo;
      af[i] = *reinterpret_cast<const s16x8*>(A + r * 32 + ((hi ^ ((r >> 1) & 3)) << 3));
    }
#pragma unroll
    for (int j = 0; j < 4; ++j) {
      int cj = wc0 + j * 16 + lo;
      bf[j] = *reinterpret_cast<const s16x8*>(B + cj * 32 + ((hi ^ ((cj >> 1) & 3)) << 3));
    }
#pragma unroll
    for (int i = 0; i < 4; ++i)
#pragma unroll
      for (int j = 0; j < 4; ++j)
        acc[i][j] = __builtin_amdgcn_mfma_f32_16x16x32_bf16(af[i], bf[j], acc[i][j], 0, 0, 0);
  };

  stageLoad(0);
  stageWrite(0, 0);
  __syncthreads();
  int cur = 0;
  for (int ks = 0; ks < 8; ++ks) {
    if (ks < 7) stageLoad(ks + 1);
    __builtin_amdgcn_sched_barrier(0);
    mma(cur);
    __builtin_amdgcn_sched_barrier(0);
    if (ks < 7) stageWrite(cur ^ 1, ks + 1);
    __syncthreads();
    cur ^= 1;
  }

  float bv[4];
#pragma unroll
  for (int fj = 0; fj < 4; ++fj) bv[fj] = bias[wc0 + fj * 16 + lo];

  if (kmode) {
    // two-half LDS transpose epilogue -> grouped kg, one u16x8 store per (m,c)
    u16x8 vout[8];
    ushort* ep = smem;  // [64][260]
#pragma unroll
    for (int h = 0; h < 2; ++h) {
      __syncthreads();
      if ((wv >> 2) == h) {
#pragma unroll
        for (int fi = 0; fi < 4; ++fi)
#pragma unroll
          for (int fj = 0; fj < 4; ++fj)
#pragma unroll
            for (int r4 = 0; r4 < 4; ++r4) {
              int rl = fi * 16 + hi * 4 + r4;
              int col = wc0 + fj * 16 + lo;
              ep[rl * 260 + col] = f2bf(phi_act(acc[fi][fj][r4] + bv[fj]));
            }
      }
      __syncthreads();
#pragma unroll
      for (int j = 0; j < 8; ++j) {
        int c = j * 32 + cl;
#pragma unroll
        for (int wl = 0; wl < 4; ++wl)
          vout[j][h * 4 + wl] = ep[(wl * 16 + m) * 260 + c];
      }
    }
#pragma unroll
    for (int j = 0; j < 8; ++j) {
      int c = j * 32 + cl;
      *reinterpret_cast<u16x8*>(
          kg + (((size_t)(b * 16 + m) * 128 + wgrp) * 256 + c) * 8) = vout[j];
    }
  } else {
#pragma unroll
    for (int fi = 0; fi < 4; ++fi)
#pragma unroll
      for (int fj = 0; fj < 4; ++fj)
#pragma unroll
        for (int r4 = 0; r4 < 4; ++r4) {
          int row = n0 + wr0 + fi * 16 + hi * 4 + r4;
          int col = wc0 + fj * 16 + lo;
          qf[((size_t)b * kQR + row) * kC + col] = f2bf(phi_act(acc[fi][fj][r4] + bv[fj]));
        }
  }
}

// ---- 3. KV GEMM per (b,m): KVT[d][c] = sum_w kg[c][w] * xg[d][w], K=1024
// tile 64x64, grid (4,4,32), BK=64, double-buffered.
__global__ __launch_bounds__(256) void kv_kernel(const ushort* __restrict__ kg,
                                                 const ushort* __restrict__ xg,
                                                 ushort* __restrict__ kvt) {
  __shared__ __align__(16) ushort smem[16384];  // 32 KB
  const int t = threadIdx.x, lane = t & 63, wv = t >> 6;
  const int cb = blockIdx.x, db = blockIdx.y, bm = blockIdx.z;
  const int lc = t & 63, g2 = t >> 6;  // staging: row lc, chunks g2 & g2+4

  u16x8 ra0, ra1, rb0, rb1;
  auto stageLoad = [&](int ws) {
    size_t base = (size_t)bm * 128 + ws * 8;
    ra0 = *reinterpret_cast<const u16x8*>(kg + ((base + g2) * 256 + cb * 64 + lc) * 8);
    ra1 = *reinterpret_cast<const u16x8*>(kg + ((base + g2 + 4) * 256 + cb * 64 + lc) * 8);
    rb0 = *reinterpret_cast<const u16x8*>(xg + ((base + g2) * 256 + db * 64 + lc) * 8);
    rb1 = *reinterpret_cast<const u16x8*>(xg + ((base + g2 + 4) * 256 + db * 64 + lc) * 8);
  };
  auto stageWrite = [&](int h) {
    ushort* A = smem + h * 4096;
    ushort* B = smem + 8192 + h * 4096;
    int s = (lc >> 1) & 7;
    *reinterpret_cast<u16x8*>(A + lc * 64 + ((g2 ^ s) << 3)) = ra0;
    *reinterpret_cast<u16x8*>(A + lc * 64 + (((g2 + 4) ^ s) << 3)) = ra1;
    *reinterpret_cast<u16x8*>(B + lc * 64 + ((g2 ^ s) << 3)) = rb0;
    *reinterpret_cast<u16x8*>(B + lc * 64 + (((g2 + 4) ^ s) << 3)) = rb1;
  };

  f32x4v acc[2][2] = {};
  const int lo = lane & 15, hi = lane >> 4;
  const int wr0 = (wv >> 1) * 32, wc0 = (wv & 1) * 32;
  auto mma = [&](int h) {
    const ushort* A = smem + h * 4096;
    const ushort* B = smem + 8192 + h * 4096;
    s16x8 af[2][2], bf[2][2];
#pragma unroll
    for (int i = 0; i < 2; ++i) {
      int r = wr0 + i * 16 + lo;
      int s = (r >> 1) & 7;
#pragma unroll
      for (int kk = 0; kk < 2; ++kk)
        af[i][kk] = *reinterpret_cast<const s16x8*>(A + r * 64 + (((kk * 4 + hi) ^ s) << 3));
    }
#pragma unroll
    for (int j = 0; j < 2; ++j) {
      int c = wc0 + j * 16 + lo;
      int s = (c >> 1) & 7;
#pragma unroll
      for (int kk = 0; kk < 2; ++kk)
        bf[j][kk] = *reinterpret_cast<const s16x8*>(B + c * 64 + (((kk * 4 + hi) ^ s) << 3));
    }
#pragma unroll
    for (int kk = 0; kk < 2; ++kk)
#pragma unroll
      for (int i = 0; i < 2; ++i)
#pragma unroll
        for (int j = 0; j < 2; ++j)
          acc[i][j] = __builtin_amdgcn_mfma_f32_16x16x32_bf16(af[i][kk], bf[j][kk], acc[i][j], 0, 0, 0);
  };

  stageLoad(0);
  stageWrite(0);
  __syncthreads();
  int cur = 0;
  for (int ws = 0; ws < 16; ++ws) {
    if (ws < 15) stageLoad(ws + 1);
    __builtin_amdgcn_sched_barrier(0);
    mma(cur);
    __builtin_amdgcn_sched_barrier(0);
    if (ws < 15) stageWrite(cur ^ 1);
    __syncthreads();
    cur ^= 1;
  }
#pragma unroll
  for (int i = 0; i < 2; ++i)
#pragma unroll
    for (int j = 0; j < 2; ++j) {
      int d = db * 64 + wc0 + j * 16 + lo;
      int c = cb * 64 + wr0 + i * 16 + hi * 4;
      u16x4 v = {f2bf(acc[i][j][0]), f2bf(acc[i][j][1]), f2bf(acc[i][j][2]),
                 f2bf(acc[i][j][3])};
      *reinterpret_cast<u16x4*>(kvt + ((size_t)bm * 256 + d) * 256 + c) = v;
    }
}

// ---- 4. out GEMM per (b,m): Out[qr*16+m][d] = qf[qr] . kvt[d] + p
__global__ __launch_bounds__(256) void out_kernel(
    const ushort* __restrict__ qf, const ushort* __restrict__ kvt,
    const float* __restrict__ EQK, const float* __restrict__ Wp,
    const float* __restrict__ bp, float* __restrict__ Out) {
  __shared__ __align__(16) ushort smem[16384];  // 32 KB
  __shared__ float Ps[128];
  const int t = threadIdx.x, lane = t & 63, wv = t >> 6;
  const int qb = blockIdx.x, db = blockIdx.y, bm = blockIdx.z;
  const int b = bm >> 4, mm = bm & 15;
  if (t < 128) {
    int qr = qb * 128 + t;
    const float* e = EQK + (((size_t)(b * 1024 + (qr >> 4)) * 16 + (qr & 15)) * 16 + mm) * 3;
    Ps[t] = e[0] * Wp[0] + e[1] * Wp[1] + e[2] * Wp[2] + bp[0];
  }
  const int r2 = t >> 2, ch = t & 3;  // staging rows r2, r2+64 at chunk ch

  u16x8 ra0, ra1, rb0, rb1;
  auto stageLoad = [&](int ks) {
    int k0 = ks * 32;
    const ushort* Aq = qf + ((size_t)b * kQR + qb * 128) * kC;
    const ushort* Bk = kvt + ((size_t)bm * 256 + db * 128) * kC;
    ra0 = *reinterpret_cast<const u16x8*>(Aq + (size_t)r2 * kC + k0 + ch * 8);
    ra1 = *reinterpret_cast<const u16x8*>(Aq + (size_t)(r2 + 64) * kC + k0 + ch * 8);
    rb0 = *reinterpret_cast<const u16x8*>(Bk + (size_t)r2 * kC + k0 + ch * 8);
    rb1 = *reinterpret_cast<const u16x8*>(Bk + (size_t)(r2 + 64) * kC + k0 + ch * 8);
  };
  auto stageWrite = [&](int h) {
    ushort* A = smem + h * 4096;
    ushort* B = smem + 8192 + h * 4096;
    *reinterpret_cast<u16x8*>(A + r2 * 32 + ((ch ^ ((r2 >> 1) & 3)) << 3)) = ra0;
    *reinterpret_cast<u16x8*>(A + (r2 + 64) * 32 + ((ch ^ (((r2 + 64) >> 1) & 3)) << 3)) = ra1;
    *reinterpret_cast<u16x8*>(B + r2 * 32 + ((ch ^ ((r2 >> 1) & 3)) << 3)) = rb0;
    *reinterpret_cast<u16x8*>(B + (r2 + 64) * 32 + ((ch ^ (((r2 + 64) >> 1) & 3)) << 3)) = rb1;
  };

  f32x4v acc[4][4] = {};
  const int lo = lane & 15, hi = lane >> 4;
  const int wr0 = (wv >> 1) * 64, wc0 = (wv & 1) * 64;
  auto mma = [&](int h) {
    const ushort* A = smem + h * 4096;
    const ushort* B = smem + 8192 + h * 4096;
    s16x8 af[4], bf[4];
#pragma unroll
    for (int i = 0; i < 4; ++i) {
      int r = wr0 + i * 16 + lo;
      af[i] = *reinterpret_cast<const s16x8*>(A + r * 32 + ((hi ^ ((r >> 1) & 3)) << 3));
    }
#pragma unroll
    for (int j = 0; j < 4; ++j) {
      int c = wc0 + j * 16 + lo;
      bf[j] = *reinterpret_cast<const s16x8*>(B + c * 32 + ((hi ^ ((c >> 1) & 3)) << 3));
    }
#pragma unroll
    for (int i = 0; i < 4; ++i)
#pragma unroll
      for (int j = 0; j < 4; ++j)
        acc[i][j] = __builtin_amdgcn_mfma_f32_16x16x32_bf16(af[i], bf[j], acc[i][j], 0, 0, 0);
  };

  stageLoad(0);
  stageWrite(0);
  __syncthreads();
  int cur = 0;
  for (int ks = 0; ks < 8; ++ks) {
    if (ks < 7) stageLoad(ks + 1);
    __builtin_amdgcn_sched_barrier(0);
    mma(cur);
    __builtin_amdgcn_sched_barrier(0);
    if (ks < 7) stageWrite(cur ^ 1);
    __syncthreads();
    cur ^= 1;
  }
#pragma unroll
  for (int fi = 0; fi < 4; ++fi)
#pragma unroll
    for (int r4 = 0; r4 < 4; ++r4) {
      int rowl = wr0 + fi * 16 + hi * 4 + r4;
      int qr = qb * 128 + rowl;
      float p = Ps[rowl];
      size_t orow = ((size_t)b * kN + (size_t)qr * 16 + mm) * kC;
#pragma unroll
      for (int fj = 0; fj < 4; ++fj) {
        int d = db * 128 + wc0 + fj * 16 + lo;
        Out[orow + d] = acc[fi][fj][r4] + p;
      }
    }
}

}  // namespace

extern "C" void kernel_launch(void* const* d_in, const int* in_sizes, int n_in,
                              void* d_out, int out_size, void* d_ws,
                              size_t ws_size, hipStream_t stream) {
  const float* input = (const float*)d_in[0];
  const float* eqk = (const float*)d_in[1];
  const float* Wq = (const float*)d_in[2];
  const float* bq = (const float*)d_in[3];
  const float* Wk = (const float*)d_in[4];
  const float* bk = (const float*)d_in[5];
  const float* Wp = (const float*)d_in[6];
  const float* bp = (const float*)d_in[7];
  float* out = (float*)d_out;

  ushort* ws = (ushort*)d_ws;
  ushort* WqT = ws;                  // 65536
  ushort* WkT = WqT + 65536;         // 65536
  ushort* xg = WkT + 65536;          // 8388608  grouped v  [bm][wgrp][c][8]
  ushort* kg = xg + 8388608;         // 8388608  grouped phi_k
  ushort* qf = kg + 8388608;         // 524288   phi_q flat [2048][256]
  ushort* kvt = qf + 524288;         // 2097152  KVT [bm][d][c]

  wt_kernel<<<dim3(4, 4, 2), 256, 0, stream>>>(Wq, Wk, WqT, WkT);
  proj_fused<<<dim3(272), 512, 0, stream>>>(input, WqT, WkT, bq, bk, xg, kg, qf);
  kv_kernel<<<dim3(4, 4, 32), 256, 0, stream>>>(kg, xg, kvt);
  out_kernel<<<dim3(8, 2, 32), 256, 0, stream>>>(qf, kvt, eqk, Wp, bp, out);
}